// Round 3
// baseline (2541.071 us; speedup 1.0000x reference)
//
#include <hip/hip_runtime.h>
#include <math.h>

constexpr int N_NODES = 500000;
constexpr int N_EDGES = 16000000;
constexpr int NXCD = 8;

// ---------------------------------------------------------------------------
// FAST PATH ws layout (floats), needs (24N + 2N + 2)*4 ≈ 52 MB:
//   [0,8N)    deg replicas   (per-XCD)
//   [8N,16N)  inagg replicas (per-XCD)
//   [16N,24N) outco replicas (per-XCD)
//   [24N,25N) dis
//   [25N,26N) y = dis*x
//   [26N,26N+2) sacc
// Replicas are updated ONLY by waves physically resident on that XCD
// (HW_REG_XCC_ID), with raw global_atomic_add_f32 (no sc bits) so the RMW
// executes in the local TCC/L2 and the line stays cached — instead of the
// device-scope fabric atomic (measured: 32 B WRITE_SIZE per atomic, 21 G/s).
// Cross-XCD visibility is only required across kernel boundaries (dispatch
// release writes back L2), never within a kernel.
// ---------------------------------------------------------------------------

__device__ __forceinline__ int xcc_id() {
    int x;
    asm volatile("s_getreg_b32 %0, hwreg(HW_REG_XCC_ID)" : "=s"(x));
    return x & (NXCD - 1);
}

__device__ __forceinline__ void tcc_atomic_add(float* p, float v) {
    // no sc0/sc1 -> executes in the issuing XCD's L2, non-returning
    asm volatile("global_atomic_add_f32 %0, %1, off" :: "v"(p), "v"(v) : "memory");
}

// ---------------- fast path kernels ----------------

__global__ __launch_bounds__(256) void k_deg_r(const int4* __restrict__ dst4,
                                               const float4* __restrict__ w4,
                                               float* __restrict__ degr) {
    int i = blockIdx.x * blockDim.x + threadIdx.x;
    float* my = degr + (size_t)xcc_id() * N_NODES;
    int4   d = dst4[i];
    float4 w = w4[i];
    tcc_atomic_add(&my[d.x], w.x);
    tcc_atomic_add(&my[d.y], w.y);
    tcc_atomic_add(&my[d.z], w.z);
    tcc_atomic_add(&my[d.w], w.w);
}

__global__ __launch_bounds__(256) void k_dis_r(const float* __restrict__ degr,
                                               const float* __restrict__ x,
                                               float* __restrict__ dis,
                                               float* __restrict__ y) {
    int i = blockIdx.x * blockDim.x + threadIdx.x;
    if (i < N_NODES) {
        float s = 1.0f;  // self-loop
#pragma unroll
        for (int r = 0; r < NXCD; ++r) s += degr[(size_t)r * N_NODES + i];
        float d = rsqrtf(s);
        dis[i] = d;
        y[i]   = d * x[i];
    }
}

__global__ __launch_bounds__(256) void k_edge_in(const int4* __restrict__ src4,
                                                 const int4* __restrict__ dst4,
                                                 const float4* __restrict__ w4,
                                                 const float* __restrict__ y,
                                                 float* __restrict__ inaggr) {
    int i = blockIdx.x * blockDim.x + threadIdx.x;
    float* my = inaggr + (size_t)xcc_id() * N_NODES;
    int4   s = src4[i];
    int4   d = dst4[i];
    float4 w = w4[i];
    tcc_atomic_add(&my[d.x], w.x * y[s.x]);
    tcc_atomic_add(&my[d.y], w.y * y[s.y]);
    tcc_atomic_add(&my[d.z], w.z * y[s.z]);
    tcc_atomic_add(&my[d.w], w.w * y[s.w]);
}

__global__ __launch_bounds__(256) void k_edge_out(const int4* __restrict__ src4,
                                                  const int4* __restrict__ dst4,
                                                  const float4* __restrict__ w4,
                                                  const float* __restrict__ dis,
                                                  float* __restrict__ outcor) {
    int i = blockIdx.x * blockDim.x + threadIdx.x;
    float* my = outcor + (size_t)xcc_id() * N_NODES;
    int4   s = src4[i];
    int4   d = dst4[i];
    float4 w = w4[i];
    tcc_atomic_add(&my[s.x], w.x * dis[d.x]);
    tcc_atomic_add(&my[s.y], w.y * dis[d.y]);
    tcc_atomic_add(&my[s.z], w.z * dis[d.z]);
    tcc_atomic_add(&my[s.w], w.w * dis[d.w]);
}

__global__ __launch_bounds__(256) void k_node_r(const float* __restrict__ dis,
                                                const float* __restrict__ x,
                                                const float* __restrict__ inaggr,
                                                const float* __restrict__ outcor,
                                                const float* __restrict__ W1,
                                                const float* __restrict__ b1,
                                                const float* __restrict__ W2,
                                                float* __restrict__ sacc) {
    int i = blockIdx.x * blockDim.x + threadIdx.x;
    float c0 = 0.0f, c1 = 0.0f;
    if (i < N_NODES) {
        float inagg = 0.0f, outco = 0.0f;
#pragma unroll
        for (int r = 0; r < NXCD; ++r) {
            inagg += inaggr[(size_t)r * N_NODES + i];
            outco += outcor[(size_t)r * N_NODES + i];
        }
        float dv   = dis[i];
        float agg1 = dv * (inagg + dv * x[i]);
        float coef = dv * outco + dv * dv;
        float h0 = 0.0f, h1 = 0.0f;
#pragma unroll
        for (int j = 0; j < 16; ++j) {
            float a = fmaxf(agg1 * W1[j] + b1[j], 0.0f);
            h0 = fmaf(a, W2[2 * j + 0], h0);
            h1 = fmaf(a, W2[2 * j + 1], h1);
        }
        c0 = coef * h0;
        c1 = coef * h1;
    }
#pragma unroll
    for (int off = 32; off > 0; off >>= 1) {
        c0 += __shfl_down(c0, off, 64);
        c1 += __shfl_down(c1, off, 64);
    }
    __shared__ float red0[4], red1[4];
    int wave = threadIdx.x >> 6;
    int lane = threadIdx.x & 63;
    if (lane == 0) { red0[wave] = c0; red1[wave] = c1; }
    __syncthreads();
    if (threadIdx.x == 0) {
        // cross-XCD accumulator: MUST be device-scope -> plain atomicAdd
        atomicAdd(&sacc[0], red0[0] + red0[1] + red0[2] + red0[3]);
        atomicAdd(&sacc[1], red1[0] + red1[1] + red1[2] + red1[3]);
    }
}

__global__ void k_final(const float* __restrict__ sacc,
                        const float* __restrict__ b2,
                        float* __restrict__ out) {
    if (threadIdx.x == 0 && blockIdx.x == 0) {
        float s0 = sacc[0] + (float)N_NODES * b2[0];
        float s1 = sacc[1] + (float)N_NODES * b2[1];
        float m  = fmaxf(s0, s1);
        float e0 = __expf(s0 - m);
        float e1 = __expf(s1 - m);
        float inv = 1.0f / (e0 + e1);
        out[0] = e0 * inv;
        out[1] = e1 * inv;
    }
}

// ---------------- fallback path (R1 code, agent-scope atomics) ----------------

__global__ __launch_bounds__(256) void k_init(float* __restrict__ deg,
                                              float* __restrict__ inagg,
                                              float* __restrict__ outco,
                                              float* __restrict__ sacc) {
    int i = blockIdx.x * blockDim.x + threadIdx.x;
    if (i < N_NODES) {
        deg[i]   = 1.0f;
        inagg[i] = 0.0f;
        outco[i] = 0.0f;
    }
    if (i < 2) sacc[i] = 0.0f;
}

__global__ __launch_bounds__(256) void k_deg(const int4* __restrict__ dst4,
                                             const float4* __restrict__ w4,
                                             float* __restrict__ deg) {
    int i = blockIdx.x * blockDim.x + threadIdx.x;
    int4   d = dst4[i];
    float4 w = w4[i];
    atomicAdd(&deg[d.x], w.x);
    atomicAdd(&deg[d.y], w.y);
    atomicAdd(&deg[d.z], w.z);
    atomicAdd(&deg[d.w], w.w);
}

__global__ __launch_bounds__(256) void k_dis(float* __restrict__ degdis,
                                             const float* __restrict__ x,
                                             float* __restrict__ y) {
    int i = blockIdx.x * blockDim.x + threadIdx.x;
    if (i < N_NODES) {
        float d = rsqrtf(degdis[i]);
        degdis[i] = d;
        y[i] = d * x[i];
    }
}

__global__ __launch_bounds__(256) void k_edge2(const int4* __restrict__ src4,
                                               const int4* __restrict__ dst4,
                                               const float4* __restrict__ w4,
                                               const float* __restrict__ dis,
                                               const float* __restrict__ y,
                                               float* __restrict__ inagg,
                                               float* __restrict__ outco) {
    int i = blockIdx.x * blockDim.x + threadIdx.x;
    int4   s = src4[i];
    int4   d = dst4[i];
    float4 w = w4[i];
    atomicAdd(&inagg[d.x], w.x * y[s.x]);
    atomicAdd(&inagg[d.y], w.y * y[s.y]);
    atomicAdd(&inagg[d.z], w.z * y[s.z]);
    atomicAdd(&inagg[d.w], w.w * y[s.w]);
    atomicAdd(&outco[s.x], w.x * dis[d.x]);
    atomicAdd(&outco[s.y], w.y * dis[d.y]);
    atomicAdd(&outco[s.z], w.z * dis[d.z]);
    atomicAdd(&outco[s.w], w.w * dis[d.w]);
}

__global__ __launch_bounds__(256) void k_node(const float* __restrict__ dis,
                                              const float* __restrict__ x,
                                              const float* __restrict__ inagg,
                                              const float* __restrict__ outco,
                                              const float* __restrict__ W1,
                                              const float* __restrict__ b1,
                                              const float* __restrict__ W2,
                                              float* __restrict__ sacc) {
    int i = blockIdx.x * blockDim.x + threadIdx.x;
    float c0 = 0.0f, c1 = 0.0f;
    if (i < N_NODES) {
        float dv   = dis[i];
        float agg1 = dv * (inagg[i] + dv * x[i]);
        float coef = dv * outco[i] + dv * dv;
        float h0 = 0.0f, h1 = 0.0f;
#pragma unroll
        for (int j = 0; j < 16; ++j) {
            float a = fmaxf(agg1 * W1[j] + b1[j], 0.0f);
            h0 = fmaf(a, W2[2 * j + 0], h0);
            h1 = fmaf(a, W2[2 * j + 1], h1);
        }
        c0 = coef * h0;
        c1 = coef * h1;
    }
#pragma unroll
    for (int off = 32; off > 0; off >>= 1) {
        c0 += __shfl_down(c0, off, 64);
        c1 += __shfl_down(c1, off, 64);
    }
    __shared__ float red0[4], red1[4];
    int wave = threadIdx.x >> 6;
    int lane = threadIdx.x & 63;
    if (lane == 0) { red0[wave] = c0; red1[wave] = c1; }
    __syncthreads();
    if (threadIdx.x == 0) {
        atomicAdd(&sacc[0], red0[0] + red0[1] + red0[2] + red0[3]);
        atomicAdd(&sacc[1], red1[0] + red1[1] + red1[2] + red1[3]);
    }
}

extern "C" void kernel_launch(void* const* d_in, const int* in_sizes, int n_in,
                              void* d_out, int out_size, void* d_ws, size_t ws_size,
                              hipStream_t stream) {
    const float* x   = (const float*)d_in[0];
    const int*   ei  = (const int*)d_in[1];     // [2, E] int32
    const float* ew  = (const float*)d_in[2];
    const float* W1  = (const float*)d_in[3];
    const float* b1  = (const float*)d_in[4];
    const float* W2  = (const float*)d_in[5];
    const float* b2  = (const float*)d_in[6];
    float* out = (float*)d_out;

    const int* src = ei;
    const int* dst = ei + N_EDGES;

    const int TB = 256;
    const int nodeBlocks = (N_NODES + TB - 1) / TB;
    const int edgeBlocks = (N_EDGES / 4) / TB;   // exact

    const size_t fastNeed = ((size_t)(3 * NXCD + 2) * N_NODES + 2) * sizeof(float);

    if (ws_size >= fastNeed) {
        float* ws     = (float*)d_ws;
        float* degr   = ws;                                  // 8N
        float* inaggr = ws + (size_t)NXCD * N_NODES;         // 8N
        float* outcor = ws + (size_t)2 * NXCD * N_NODES;     // 8N
        float* dis    = ws + (size_t)3 * NXCD * N_NODES;     // N
        float* y      = dis + N_NODES;                       // N
        float* sacc   = y + N_NODES;                         // 2

        hipMemsetAsync(ws, 0, (size_t)3 * NXCD * N_NODES * sizeof(float), stream);
        hipMemsetAsync(sacc, 0, 2 * sizeof(float), stream);

        k_deg_r<<<edgeBlocks, TB, 0, stream>>>((const int4*)dst, (const float4*)ew, degr);
        k_dis_r<<<nodeBlocks, TB, 0, stream>>>(degr, x, dis, y);
        k_edge_in<<<edgeBlocks, TB, 0, stream>>>((const int4*)src, (const int4*)dst,
                                                 (const float4*)ew, y, inaggr);
        k_edge_out<<<edgeBlocks, TB, 0, stream>>>((const int4*)src, (const int4*)dst,
                                                  (const float4*)ew, dis, outcor);
        k_node_r<<<nodeBlocks, TB, 0, stream>>>(dis, x, inaggr, outcor, W1, b1, W2, sacc);
        k_final<<<1, 64, 0, stream>>>(sacc, b2, out);
    } else {
        float* ws     = (float*)d_ws;
        float* degdis = ws;
        float* y      = ws + N_NODES;
        float* inagg  = ws + 2 * N_NODES;
        float* outco  = ws + 3 * N_NODES;
        float* sacc   = ws + 4 * N_NODES;

        k_init<<<nodeBlocks, TB, 0, stream>>>(degdis, inagg, outco, sacc);
        k_deg<<<edgeBlocks, TB, 0, stream>>>((const int4*)dst, (const float4*)ew, degdis);
        k_dis<<<nodeBlocks, TB, 0, stream>>>(degdis, x, y);
        k_edge2<<<edgeBlocks, TB, 0, stream>>>((const int4*)src, (const int4*)dst,
                                               (const float4*)ew, degdis, y, inagg, outco);
        k_node<<<nodeBlocks, TB, 0, stream>>>(degdis, x, inagg, outco, W1, b1, W2, sacc);
        k_final<<<1, 64, 0, stream>>>(sacc, b2, out);
    }
}